// Round 1
// baseline (563.053 us; speedup 1.0000x reference)
//
#include <hip/hip_runtime.h>
#include <math.h>

// Problem constants (B=1, S=8, N=M=768, D=64, IT=16, RATIO=0.6, THR=0.75, K=8)
#define NN 768
#define MM 768
#define DD 64
#define BI 8            // B*S
#define RN 460          // int(0.6*768) sampled rows/cols
#define KTOP 8

// Output layout (concatenated flat, return order: ti, tm, topk_err), all f32
static constexpr size_t OFF_TI = 0;                                  // (1,8,768,768)
static constexpr size_t OFF_TM = (size_t)KTOP * NN * MM;             // 4718592, (1,8,64,64)
static constexpr size_t OFF_TE = OFF_TM + (size_t)KTOP * DD * DD;    // 4751360, (1,8)

// Workspace layout (float indices, then raw-byte tail for accumulators)
static constexpr size_t T_OFF     = 0;                                    // t: (8,460,64)
static constexpr size_t MODEL_OFF = T_OFF + (size_t)BI * RN * DD;         // 235520: models (8,64,64)
static constexpr size_t XT_OFF    = MODEL_OFF + (size_t)BI * DD * DD;     // 268288: xt (8,768,64)
static constexpr size_t ERR_OFF   = XT_OFF + (size_t)BI * NN * DD;        // 661504: err (8,768,768)
static constexpr size_t FLOATS_END = ERR_OFF + (size_t)BI * NN * MM;      // 5380096 floats
static constexpr size_t SUM_BYTE  = FLOATS_END * 4;   // double[8]  (8-aligned)
static constexpr size_t CNT_BYTE  = SUM_BYTE + 64;    // int[8]
static constexpr size_t DEN_BYTE  = CNT_BYTE + 32;    // int[8]
static constexpr size_t ORD_BYTE  = DEN_BYTE + 32;    // int[8]
static constexpr size_t FLAG_BYTE = ORD_BYTE + 32;    // int[1] mask-layout flag

// Mask element accessor: flag==1 -> int32 storage, flag==0 -> 1-byte storage.
__device__ __forceinline__ int ldm(const void* p, int flag, size_t idx) {
  if (flag) return ((const int*)p)[idx] != 0;
  return ((const unsigned char*)p)[idx] != 0;
}

// Detect mask storage layout: int32 0/1 values have zero bytes at offsets %4 != 0.
__global__ void k_detect(const unsigned char* __restrict__ q, int* __restrict__ flag) {
  __shared__ int found;
  if (threadIdx.x == 0) found = 0;
  __syncthreads();
  int f = 0;
  for (int i = threadIdx.x; i < 4096; i += 256)
    if ((i & 3) && q[i]) f = 1;
  if (f) atomicOr(&found, 1);
  __syncthreads();
  if (threadIdx.x == 0) *flag = found ? 0 : 1;   // 1 => int32 layout
}

// Kernel A: t[b,n,e] = sum_{m<460} mask[b,n,m]*y[b,m,e] for n<460; den[b] += sum_m mask
// One wave per (b,n); lane = e. Mask loads are wave-uniform -> uniform branch.
__global__ __launch_bounds__(256) void k_accum_t(
    const float* __restrict__ kks, const void* __restrict__ qm, const void* __restrict__ km,
    const int* __restrict__ flagp, float* __restrict__ tbuf, int* __restrict__ den) {
  int b = blockIdx.y;
  int n = blockIdx.x * 4 + (threadIdx.x >> 6);
  int lane = threadIdx.x & 63;
  int flag = *flagp;
  const float* yb = kks + (size_t)b * MM * DD;
  size_t mrow = ((size_t)b * NN + n) * MM;
  float acc = 0.f;
  int cnt = 0;
#pragma unroll 4
  for (int m = 0; m < RN; ++m) {
    int ms = ldm(qm, flag, mrow + m) & ldm(km, flag, mrow + m);
    if (ms) { acc += yb[(size_t)m * DD + lane]; cnt++; }
  }
  tbuf[T_OFF + ((size_t)b * RN + n) * DD + lane] = acc;
  if (lane == 0) atomicAdd(&den[b], cnt);
}

// Kernel B: model[b,d,e] = (sum_{n<460} x[n,d]*t[b,n,e]) / (den[b]+1e-6)
__global__ __launch_bounds__(256) void k_num(
    const float* __restrict__ qk, const float* __restrict__ wsf,
    const int* __restrict__ den, float* __restrict__ model) {
  __shared__ float xs[16 * 64];
  __shared__ float ts[16 * 64];
  int b = blockIdx.x;
  int tid = threadIdx.x;
  int e = tid & 63, dg = tid >> 6;          // dg uniform per wave -> LDS broadcast
  const float* tbuf = wsf + T_OFF;
  float acc[16];
#pragma unroll
  for (int i = 0; i < 16; i++) acc[i] = 0.f;
  for (int c0 = 0; c0 < RN; c0 += 16) {
    for (int l = tid; l < 1024; l += 256) {
      int r = l >> 6, col = l & 63;
      int n = c0 + r;
      xs[l] = (n < RN) ? qk[(size_t)n * DD + col] : 0.f;
      ts[l] = (n < RN) ? tbuf[((size_t)b * RN + n) * DD + col] : 0.f;
    }
    __syncthreads();
#pragma unroll 4
    for (int r = 0; r < 16; r++) {
      float tv = ts[r * 64 + e];
#pragma unroll
      for (int i = 0; i < 16; i++) acc[i] += xs[r * 64 + dg + i * 4] * tv;
    }
    __syncthreads();
  }
  float denf = (float)den[b] + 1e-6f;
#pragma unroll
  for (int i = 0; i < 16; i++) {
    int d = dg + i * 4;
    model[(size_t)b * (DD * DD) + (size_t)d * DD + e] = acc[i] / denf;
  }
}

// Kernel C: xt[b,n,e] = sum_d x[n,d]*model[b,d,e]; one wave per (b,n), model staged in LDS
__global__ __launch_bounds__(256) void k_xt(
    const float* __restrict__ qk, const float* __restrict__ model, float* __restrict__ xt) {
  __shared__ float ml[DD * DD];
  int b = blockIdx.y;
  int tid = threadIdx.x;
  for (int l = tid; l < DD * DD; l += 256) ml[l] = model[(size_t)b * DD * DD + l];
  __syncthreads();
  int n = blockIdx.x * 4 + (tid >> 6);
  int lane = tid & 63;
  float acc = 0.f;
#pragma unroll 8
  for (int d = 0; d < DD; d++) acc += qk[(size_t)n * DD + d] * ml[d * DD + lane];
  xt[((size_t)b * NN + n) * DD + lane] = acc;
}

// Kernel D: err[b,i,j] = mask ? ||xt_i||^2 + ||y_j||^2 - 2*xt_i.y_j : +INF
// 64x64 f32 tile GEMM (K=64 single pass), per-block sum/count -> global atomics.
__global__ __launch_bounds__(256) void k_err(
    const float* __restrict__ xt, const float* __restrict__ kks,
    const void* __restrict__ qm, const void* __restrict__ km, const int* __restrict__ flagp,
    float* __restrict__ err, double* __restrict__ sumb, int* __restrict__ cntb) {
  __shared__ float As[64 * 68];   // pad 68: float4-aligned rows (272B), compute-phase conflict-free
  __shared__ float Bs[64 * 68];
  __shared__ float xx_s[64], yy_s[64];
  __shared__ float rsum[256];
  __shared__ int rcnt[256];
  int b = blockIdx.z;
  int i0 = blockIdx.y * 64, j0 = blockIdx.x * 64;
  int tid = threadIdx.x;
  int tx = tid & 15, ty = tid >> 4;
  const float* xb = xt + ((size_t)b * NN + i0) * DD;
  const float* yb = kks + ((size_t)b * MM + j0) * DD;
  for (int q = tid; q < 1024; q += 256) {
    int r = q >> 4, c = q & 15;
    float4 va = ((const float4*)(xb + (size_t)r * DD))[c];
    float4 vb = ((const float4*)(yb + (size_t)r * DD))[c];
    *(float4*)&As[r * 68 + c * 4] = va;
    *(float4*)&Bs[r * 68 + c * 4] = vb;
  }
  __syncthreads();
  if (tid < 64) {
    float s = 0.f;
#pragma unroll 8
    for (int k2 = 0; k2 < 64; k2++) { float v = As[tid * 68 + k2]; s += v * v; }
    xx_s[tid] = s;
  } else if (tid < 128) {
    int r = tid - 64;
    float s = 0.f;
#pragma unroll 8
    for (int k2 = 0; k2 < 64; k2++) { float v = Bs[r * 68 + k2]; s += v * v; }
    yy_s[r] = s;
  }
  __syncthreads();
  float acc[4][4];
#pragma unroll
  for (int ii = 0; ii < 4; ii++)
#pragma unroll
    for (int jj = 0; jj < 4; jj++) acc[ii][jj] = 0.f;
  for (int k2 = 0; k2 < 64; k2 += 4) {
    float4 av[4], bv[4];
#pragma unroll
    for (int ii = 0; ii < 4; ii++) av[ii] = *(const float4*)&As[(ty + 16 * ii) * 68 + k2];
#pragma unroll
    for (int jj = 0; jj < 4; jj++) bv[jj] = *(const float4*)&Bs[(tx + 16 * jj) * 68 + k2];
#pragma unroll
    for (int ii = 0; ii < 4; ii++)
#pragma unroll
      for (int jj = 0; jj < 4; jj++)
        acc[ii][jj] += av[ii].x * bv[jj].x + av[ii].y * bv[jj].y +
                       av[ii].z * bv[jj].z + av[ii].w * bv[jj].w;
  }
  int flag = *flagp;
  const float INF = __builtin_inff();
  float psum = 0.f;
  int pcnt = 0;
#pragma unroll
  for (int ii = 0; ii < 4; ii++) {
#pragma unroll
    for (int jj = 0; jj < 4; jj++) {
      int i = i0 + ty + 16 * ii, j = j0 + tx + 16 * jj;
      size_t idx = ((size_t)b * NN + i) * MM + j;
      int ms = ldm(qm, flag, idx) & ldm(km, flag, idx);
      float v = xx_s[ty + 16 * ii] + yy_s[tx + 16 * jj] - 2.f * acc[ii][jj];
      if (ms) { err[idx] = v; psum += v; pcnt++; }
      else    { err[idx] = INF; }
    }
  }
  rsum[tid] = psum;
  rcnt[tid] = pcnt;
  __syncthreads();
  for (int s = 128; s > 0; s >>= 1) {
    if (tid < s) { rsum[tid] += rsum[tid + s]; rcnt[tid] += rcnt[tid + s]; }
    __syncthreads();
  }
  if (tid == 0) {
    atomicAdd(&sumb[b], (double)rsum[0]);
    atomicAdd(&cntb[b], rcnt[0]);
  }
}

// Kernel E: avg[b] = sum/cnt; rank descending (stable, = lax.top_k with K=S); write
// topk_err and gather reordered models into d_out; store order for kernel F.
__global__ __launch_bounds__(256) void k_rank(
    const double* __restrict__ sumb, const int* __restrict__ cntb,
    const float* __restrict__ model, int* __restrict__ order, float* __restrict__ out) {
  __shared__ int ord_s[BI];
  if (threadIdx.x == 0) {
    float avg[BI];
    bool used[BI];
    for (int b = 0; b < BI; b++) { avg[b] = (float)(sumb[b] / (double)cntb[b]); used[b] = false; }
    for (int k = 0; k < KTOP; k++) {
      int best = -1;
      float bv = -__builtin_inff();
      for (int b = 0; b < BI; b++)
        if (!used[b] && avg[b] > bv) { bv = avg[b]; best = b; }
      used[best] = true;
      ord_s[k] = best;
      order[k] = best;
      out[OFF_TE + k] = avg[best];
    }
  }
  __syncthreads();
  for (int l = threadIdx.x; l < KTOP * DD * DD; l += 256) {
    int k = l >> 12;
    out[OFF_TM + l] = model[(size_t)ord_s[k] * DD * DD + (l & (DD * DD - 1))];
  }
}

// Kernel F: per output row (k,n): b=order[k]; 0.75 linear-interp nanquantile over m
// (masked entries stored as +INF -> sort to end, excluded via cnt), write inliers 0/1.
__global__ __launch_bounds__(256) void k_quant(
    const float* __restrict__ err, const int* __restrict__ order, float* __restrict__ out) {
  __shared__ float orig[768];
  __shared__ float sb[1024];
  __shared__ int rint[256];
  __shared__ int cnt_sh;
  int k = blockIdx.y, n = blockIdx.x, tid = threadIdx.x;
  int b = order[k];
  const float* row = err + ((size_t)b * NN + n) * MM;
  const float INF = __builtin_inff();
  int c = 0;
#pragma unroll
  for (int r = 0; r < 3; r++) {
    int m = tid + 256 * r;
    float v = row[m];
    orig[m] = v;
    sb[m] = v;
    if (v < INF) c++;
  }
  sb[768 + tid] = INF;
  rint[tid] = c;
  __syncthreads();
  for (int s = 128; s > 0; s >>= 1) {
    if (tid < s) rint[tid] += rint[tid + s];
    __syncthreads();
  }
  if (tid == 0) cnt_sh = rint[0];
  // bitonic sort ascending, 1024 elements, 256 threads
  for (unsigned ksz = 2; ksz <= 1024; ksz <<= 1) {
    for (unsigned j = ksz >> 1; j > 0; j >>= 1) {
      __syncthreads();
      for (unsigned t = tid; t < 1024; t += 256) {
        unsigned ixj = t ^ j;
        if (ixj > t) {
          float a = sb[t], bb = sb[ixj];
          bool up = ((t & ksz) == 0);
          if (up ? (a > bb) : (a < bb)) { sb[t] = bb; sb[ixj] = a; }
        }
      }
    }
  }
  __syncthreads();
  int cnt = cnt_sh;
  float thr;
  if (cnt == 0) {
    thr = -INF;
  } else {
    float pos = 0.75f * (float)(cnt - 1);   // exact in f32 (x*3/4, x < 2^10)
    int k0 = (int)pos;
    float f = pos - (float)k0;
    float a = sb[k0];
    float b2 = (k0 + 1 < cnt) ? sb[k0 + 1] : a;
    thr = a + f * (b2 - a);
  }
  size_t obase = ((size_t)k * NN + n) * MM;
#pragma unroll
  for (int r = 0; r < 3; r++) {
    int m = tid + 256 * r;
    out[OFF_TI + obase + m] = (orig[m] < thr) ? 1.0f : 0.0f;
  }
}

extern "C" void kernel_launch(void* const* d_in, const int* in_sizes, int n_in,
                              void* d_out, int out_size, void* d_ws, size_t ws_size,
                              hipStream_t stream) {
  (void)in_sizes; (void)n_in; (void)out_size; (void)ws_size;
  const float* qk  = (const float*)d_in[0];   // (1,768,64)
  const float* kks = (const float*)d_in[1];   // (1,8,768,64)
  const void*  qm  = d_in[2];                 // (8,768,768) bool/int
  const void*  km  = d_in[3];                 // (8,768,768) bool/int
  // d_in[4], d_in[5] = perm1, perm2: permutations of [0,460) -> solver sums are
  // permutation-invariant, models identical across IT; perms unused.
  float* out = (float*)d_out;

  float* wsf = (float*)d_ws;
  char*  wsb = (char*)d_ws;
  float* tbuf  = wsf;                      // indexed with T_OFF inside kernel
  float* model = wsf + MODEL_OFF;
  float* xtb   = wsf + XT_OFF;
  float* errb  = wsf + ERR_OFF;
  double* sumb = (double*)(wsb + SUM_BYTE);
  int* cntb  = (int*)(wsb + CNT_BYTE);
  int* den   = (int*)(wsb + DEN_BYTE);
  int* order = (int*)(wsb + ORD_BYTE);
  int* flagp = (int*)(wsb + FLAG_BYTE);

  // zero accumulators (ws is poisoned 0xAA before every call)
  hipMemsetAsync(wsb + SUM_BYTE, 0, 256, stream);
  k_detect<<<1, 256, 0, stream>>>((const unsigned char*)qm, flagp);
  k_accum_t<<<dim3(RN / 4, BI), 256, 0, stream>>>(kks, qm, km, flagp, tbuf, den);
  k_num<<<BI, 256, 0, stream>>>(qk, wsf, den, model);
  k_xt<<<dim3(NN / 4, BI), 256, 0, stream>>>(qk, model, xtb);
  k_err<<<dim3(MM / 64, NN / 64, BI), 256, 0, stream>>>(xtb, kks, qm, km, flagp, errb, sumb, cntb);
  k_rank<<<1, 256, 0, stream>>>(sumb, cntb, model, order, out);
  k_quant<<<dim3(NN, KTOP), 256, 0, stream>>>(errb, order, out);
}

// Round 2
// 262.326 us; speedup vs baseline: 2.1464x; 2.1464x over previous
//
#include <hip/hip_runtime.h>
#include <math.h>

// Problem constants (B=1, S=8, N=M=768, D=64, IT=16, RATIO=0.6, THR=0.75, K=8)
#define NN 768
#define MM 768
#define DD 64
#define BI 8            // B*S
#define RN 460          // int(0.6*768) sampled rows/cols
#define KTOP 8

// Output layout (concatenated flat, return order: ti, tm, topk_err), all f32
static constexpr size_t OFF_TI = 0;                                  // (1,8,768,768)
static constexpr size_t OFF_TM = (size_t)KTOP * NN * MM;             // (1,8,64,64)
static constexpr size_t OFF_TE = OFF_TM + (size_t)KTOP * DD * DD;    // (1,8)

// Workspace layout (float indices, then raw-byte tail)
static constexpr size_t T_OFF     = 0;                                    // t: (8,460,64)
static constexpr size_t NUM_OFF   = T_OFF + (size_t)BI * RN * DD;         // num (8,64,64) (model numerator)
static constexpr size_t XT_OFF    = NUM_OFF + (size_t)BI * DD * DD;       // xt (8,768,64)
static constexpr size_t ERR_OFF   = XT_OFF + (size_t)BI * NN * DD;        // err (8,768,768)
static constexpr size_t FLOATS_END = ERR_OFF + (size_t)BI * NN * MM;
static constexpr size_t SUM_BYTE  = FLOATS_END * 4;   // double[8]
static constexpr size_t CNT_BYTE  = SUM_BYTE + 64;    // int[8]
static constexpr size_t DEN_BYTE  = CNT_BYTE + 32;    // int[8]
static constexpr size_t ORD_BYTE  = DEN_BYTE + 32;    // int[8]
static constexpr size_t FLAG_BYTE = ORD_BYTE + 32;    // int[1]
static constexpr size_t PM_BYTE   = SUM_BYTE + 256;   // uint64[8*768*16] packed combined mask

__device__ __forceinline__ int ldm(const void* p, int flag, size_t idx) {
  if (flag) return ((const int*)p)[idx] != 0;
  return ((const unsigned char*)p)[idx] != 0;
}

// Detect mask storage layout: int32 0/1 values have zero bytes at offsets %4 != 0.
__global__ void k_detect(const unsigned char* __restrict__ q, int* __restrict__ flag) {
  __shared__ int found;
  if (threadIdx.x == 0) found = 0;
  __syncthreads();
  int f = 0;
  for (int i = threadIdx.x; i < 4096; i += 256)
    if ((i & 3) && q[i]) f = 1;
  if (f) atomicOr(&found, 1);
  __syncthreads();
  if (threadIdx.x == 0) *flag = found ? 0 : 1;   // 1 => int32 layout
}

// Pack combined mask qm&km into bitmask words: pm[(b*768+i)*16 + w] covers j = w*64..w*64+63.
// One wave per row; 12 ballots. Coalesced mask reads (this is the one full read of the masks).
__global__ __launch_bounds__(256) void k_pack(
    const void* __restrict__ qm, const void* __restrict__ km, const int* __restrict__ flagp,
    unsigned long long* __restrict__ pm) {
  int b = blockIdx.y;
  int i = blockIdx.x * 4 + (threadIdx.x >> 6);
  int lane = threadIdx.x & 63;
  int flag = *flagp;
  size_t row = ((size_t)b * NN + i) * MM;
  size_t prow = ((size_t)b * NN + i) * 16;
#pragma unroll
  for (int w = 0; w < 12; w++) {
    int j = w * 64 + lane;
    int ms = ldm(qm, flag, row + j) & ldm(km, flag, row + j);
    unsigned long long bl = __ballot(ms);
    if (lane == 0) pm[prow + w] = bl;
  }
}

// Kernel A: t[b,n,e] = sum_{m<460} mask[b,n,m]*y[b,m,e] for n<460; den[b] += popcount
// One wave per (b,n); walk set bits of 8 mask words; each add is a coalesced 256B y-row load.
__global__ __launch_bounds__(256) void k_accum_t(
    const float* __restrict__ kks, const unsigned long long* __restrict__ pm,
    float* __restrict__ tbuf, int* __restrict__ den) {
  int b = blockIdx.y;
  int n = blockIdx.x * 4 + (threadIdx.x >> 6);
  int lane = threadIdx.x & 63;
  const float* yb = kks + (size_t)b * MM * DD;
  size_t prow = ((size_t)b * NN + n) * 16;
  float acc = 0.f;
  int cnt = 0;
#pragma unroll
  for (int w = 0; w < 8; w++) {
    unsigned long long bits = pm[prow + w];
    if (w == 7) bits &= 0xFFFULL;          // m < 460 (448 + 12)
    cnt += __builtin_popcountll(bits);
    while (bits) {
      int m = w * 64 + __builtin_ctzll(bits);
      bits &= bits - 1;
      acc += yb[(size_t)m * DD + lane];
    }
  }
  tbuf[T_OFF + ((size_t)b * RN + n) * DD + lane] = acc;
  if (lane == 0) atomicAdd(&den[b], cnt);
}

// Kernel B: num[b,d,e] += sum_{n in split} x[n,d]*t[b,n,e]  (K-split over 4 blocks, float atomics)
__global__ __launch_bounds__(256) void k_num(
    const float* __restrict__ qk, const float* __restrict__ wsf, float* __restrict__ num) {
  __shared__ float xs[16 * 64];
  __shared__ float ts[16 * 64];
  int b = blockIdx.y;
  int n_beg = blockIdx.x * 115, n_end = n_beg + 115;   // 4*115 = 460
  int tid = threadIdx.x;
  int e = tid & 63, dg = tid >> 6;
  const float* tbuf = wsf + T_OFF;
  float acc[16];
#pragma unroll
  for (int i = 0; i < 16; i++) acc[i] = 0.f;
  for (int c0 = n_beg; c0 < n_end; c0 += 16) {
    for (int l = tid; l < 1024; l += 256) {
      int r = l >> 6, col = l & 63;
      int n = c0 + r;
      xs[l] = (n < n_end) ? qk[(size_t)n * DD + col] : 0.f;
      ts[l] = (n < n_end) ? tbuf[((size_t)b * RN + n) * DD + col] : 0.f;
    }
    __syncthreads();
#pragma unroll 4
    for (int r = 0; r < 16; r++) {
      float tv = ts[r * 64 + e];
#pragma unroll
      for (int i = 0; i < 16; i++) acc[i] += xs[r * 64 + dg + i * 4] * tv;
    }
    __syncthreads();
  }
#pragma unroll
  for (int i = 0; i < 16; i++) {
    int d = dg + i * 4;
    atomicAdd(&num[(size_t)b * (DD * DD) + (size_t)d * DD + e], acc[i]);
  }
}

// Kernel C: xt[b,n,e] = sum_d x[n,d]*num[b,d,e]/den[b]
__global__ __launch_bounds__(256) void k_xt(
    const float* __restrict__ qk, const float* __restrict__ num, const int* __restrict__ den,
    float* __restrict__ xt) {
  __shared__ float ml[DD * DD];
  int b = blockIdx.y;
  int tid = threadIdx.x;
  float inv = 1.f / ((float)den[b] + 1e-6f);
  for (int l = tid; l < DD * DD; l += 256) ml[l] = num[(size_t)b * DD * DD + l] * inv;
  __syncthreads();
  int n = blockIdx.x * 4 + (tid >> 6);
  int lane = tid & 63;
  float acc = 0.f;
#pragma unroll 8
  for (int d = 0; d < DD; d++) acc += qk[(size_t)n * DD + d] * ml[d * DD + lane];
  xt[((size_t)b * NN + n) * DD + lane] = acc;
}

// Kernel D: err[b,i,j] = mask ? ||xt_i||^2 + ||y_j||^2 - 2*xt_i.y_j : +INF
// 64x64 f32 tile GEMM; mask from packed bits (word index = j-tile index).
__global__ __launch_bounds__(256) void k_err(
    const float* __restrict__ xt, const float* __restrict__ kks,
    const unsigned long long* __restrict__ pm,
    float* __restrict__ err, double* __restrict__ sumb, int* __restrict__ cntb) {
  __shared__ float As[64 * 68];
  __shared__ float Bs[64 * 68];
  __shared__ float xx_s[64], yy_s[64];
  __shared__ float rsum[256];
  __shared__ int rcnt[256];
  int b = blockIdx.z;
  int wj = blockIdx.x;                     // j-word index (64-aligned tile)
  int i0 = blockIdx.y * 64, j0 = wj * 64;
  int tid = threadIdx.x;
  int tx = tid & 15, ty = tid >> 4;
  const float* xb = xt + ((size_t)b * NN + i0) * DD;
  const float* yb = kks + ((size_t)b * MM + j0) * DD;
  for (int q = tid; q < 1024; q += 256) {
    int r = q >> 4, c = q & 15;
    float4 va = ((const float4*)(xb + (size_t)r * DD))[c];
    float4 vb = ((const float4*)(yb + (size_t)r * DD))[c];
    *(float4*)&As[r * 68 + c * 4] = va;
    *(float4*)&Bs[r * 68 + c * 4] = vb;
  }
  __syncthreads();
  if (tid < 64) {
    float s = 0.f;
#pragma unroll 8
    for (int k2 = 0; k2 < 64; k2++) { float v = As[tid * 68 + k2]; s += v * v; }
    xx_s[tid] = s;
  } else if (tid < 128) {
    int r = tid - 64;
    float s = 0.f;
#pragma unroll 8
    for (int k2 = 0; k2 < 64; k2++) { float v = Bs[r * 68 + k2]; s += v * v; }
    yy_s[r] = s;
  }
  __syncthreads();
  float acc[4][4];
#pragma unroll
  for (int ii = 0; ii < 4; ii++)
#pragma unroll
    for (int jj = 0; jj < 4; jj++) acc[ii][jj] = 0.f;
  for (int k2 = 0; k2 < 64; k2 += 4) {
    float4 av[4], bv[4];
#pragma unroll
    for (int ii = 0; ii < 4; ii++) av[ii] = *(const float4*)&As[(ty + 16 * ii) * 68 + k2];
#pragma unroll
    for (int jj = 0; jj < 4; jj++) bv[jj] = *(const float4*)&Bs[(tx + 16 * jj) * 68 + k2];
#pragma unroll
    for (int ii = 0; ii < 4; ii++)
#pragma unroll
      for (int jj = 0; jj < 4; jj++)
        acc[ii][jj] += av[ii].x * bv[jj].x + av[ii].y * bv[jj].y +
                       av[ii].z * bv[jj].z + av[ii].w * bv[jj].w;
  }
  const float INF = __builtin_inff();
  float psum = 0.f;
  int pcnt = 0;
#pragma unroll
  for (int ii = 0; ii < 4; ii++) {
    int i = i0 + ty + 16 * ii;
    unsigned long long word = pm[((size_t)b * NN + i) * 16 + wj];
#pragma unroll
    for (int jj = 0; jj < 4; jj++) {
      int j = j0 + tx + 16 * jj;
      size_t idx = ((size_t)b * NN + i) * MM + j;
      int ms = (int)((word >> (tx + 16 * jj)) & 1ULL);
      float v = xx_s[ty + 16 * ii] + yy_s[tx + 16 * jj] - 2.f * acc[ii][jj];
      if (ms) { err[idx] = v; psum += v; pcnt++; }
      else    { err[idx] = INF; }
    }
  }
  rsum[tid] = psum;
  rcnt[tid] = pcnt;
  __syncthreads();
  for (int s = 128; s > 0; s >>= 1) {
    if (tid < s) { rsum[tid] += rsum[tid + s]; rcnt[tid] += rcnt[tid + s]; }
    __syncthreads();
  }
  if (tid == 0) {
    atomicAdd(&sumb[b], (double)rsum[0]);
    atomicAdd(&cntb[b], rcnt[0]);
  }
}

// Kernel E: rank batches by avg err descending (== top_k with K=S); write topk_err + models.
__global__ __launch_bounds__(256) void k_rank(
    const double* __restrict__ sumb, const int* __restrict__ cntb,
    const float* __restrict__ num, const int* __restrict__ den,
    int* __restrict__ order, float* __restrict__ out) {
  __shared__ int ord_s[BI];
  __shared__ float invd_s[BI];
  if (threadIdx.x == 0) {
    float avg[BI];
    bool used[BI];
    for (int b = 0; b < BI; b++) { avg[b] = (float)(sumb[b] / (double)cntb[b]); used[b] = false; }
    for (int k = 0; k < KTOP; k++) {
      int best = -1;
      float bv = -__builtin_inff();
      for (int b = 0; b < BI; b++)
        if (!used[b] && avg[b] > bv) { bv = avg[b]; best = b; }
      used[best] = true;
      ord_s[k] = best;
      order[k] = best;
      invd_s[k] = 1.f / ((float)den[best] + 1e-6f);
      out[OFF_TE + k] = avg[best];
    }
  }
  __syncthreads();
  for (int l = threadIdx.x; l < KTOP * DD * DD; l += 256) {
    int k = l >> 12;
    out[OFF_TM + l] = num[(size_t)ord_s[k] * DD * DD + (l & (DD * DD - 1))] * invd_s[k];
  }
}

__device__ __forceinline__ unsigned f2key(float f) {
  unsigned u = __float_as_uint(f);
  return (u & 0x80000000u) ? ~u : (u | 0x80000000u);
}
__device__ __forceinline__ float key2f(unsigned k) {
  unsigned u = (k & 0x80000000u) ? (k ^ 0x80000000u) : ~k;
  return __uint_as_float(u);
}

// Kernel F: one WAVE per (k,n) row. errs in registers; exact k-th/(k+1)-th smallest via
// 32-step binary search on sortable uint keys with ballot counting. No LDS, no barriers.
__global__ __launch_bounds__(256) void k_quant(
    const float* __restrict__ err, const int* __restrict__ order, float* __restrict__ out) {
  int kk = blockIdx.y;
  int n = blockIdx.x * 4 + (threadIdx.x >> 6);
  int lane = threadIdx.x & 63;
  int b = order[kk];
  const float* row = err + ((size_t)b * NN + n) * MM;
  const float INF = __builtin_inff();
  float v[12];
  unsigned key[12];
#pragma unroll
  for (int w = 0; w < 3; w++) {
    float4 f4 = ((const float4*)row)[w * 64 + lane];
    v[w * 4 + 0] = f4.x; v[w * 4 + 1] = f4.y; v[w * 4 + 2] = f4.z; v[w * 4 + 3] = f4.w;
  }
  int cnt = 0;
#pragma unroll
  for (int r = 0; r < 12; r++) {
    key[r] = f2key(v[r]);
    cnt += __builtin_popcountll(__ballot(v[r] < INF));
  }
  float thr;
  if (cnt == 0) {
    thr = -INF;
  } else {
    float pos = 0.75f * (float)(cnt - 1);
    int k0 = (int)pos;
    float f = pos - (float)k0;
    // binary search: smallest key with count(<= key) >= k0+1  (exact k0-th smallest)
    unsigned lo = 0u, hi = 0xFFFFFFFFu;
    int target = k0 + 1;
    while (lo < hi) {
      unsigned mid = lo + ((hi - lo) >> 1);
      int c = 0;
#pragma unroll
      for (int r = 0; r < 12; r++) c += __builtin_popcountll(__ballot(key[r] <= mid));
      if (c >= target) hi = mid; else lo = mid + 1;
    }
    unsigned ka = lo;
    float a = key2f(ka);
    float b2;
    if (k0 + 1 >= cnt) {
      b2 = a;
    } else {
      int c1 = 0;
#pragma unroll
      for (int r = 0; r < 12; r++) c1 += __builtin_popcountll(__ballot(key[r] <= ka));
      if (c1 >= k0 + 2) {
        b2 = a;                           // duplicate value covers rank k0+1
      } else {
        unsigned mn = 0xFFFFFFFFu;
#pragma unroll
        for (int r = 0; r < 12; r++) mn = min(mn, (key[r] > ka) ? key[r] : 0xFFFFFFFFu);
#pragma unroll
        for (int off = 32; off > 0; off >>= 1) {
          unsigned o = (unsigned)__shfl_xor((int)mn, off);
          mn = min(mn, o);
        }
        b2 = key2f(mn);
      }
    }
    thr = a + f * (b2 - a);
  }
  float* orow = out + OFF_TI + ((size_t)kk * NN + n) * MM;
#pragma unroll
  for (int w = 0; w < 3; w++) {
    float4 o;
    o.x = (v[w * 4 + 0] < thr) ? 1.f : 0.f;
    o.y = (v[w * 4 + 1] < thr) ? 1.f : 0.f;
    o.z = (v[w * 4 + 2] < thr) ? 1.f : 0.f;
    o.w = (v[w * 4 + 3] < thr) ? 1.f : 0.f;
    ((float4*)orow)[w * 64 + lane] = o;
  }
}

extern "C" void kernel_launch(void* const* d_in, const int* in_sizes, int n_in,
                              void* d_out, int out_size, void* d_ws, size_t ws_size,
                              hipStream_t stream) {
  (void)in_sizes; (void)n_in; (void)out_size; (void)ws_size;
  const float* qk  = (const float*)d_in[0];   // (1,768,64)
  const float* kks = (const float*)d_in[1];   // (1,8,768,64)
  const void*  qm  = d_in[2];                 // (8,768,768) bool/int
  const void*  km  = d_in[3];                 // (8,768,768) bool/int
  // perm1/perm2 unused: permutations make the solver sums iteration-invariant.
  float* out = (float*)d_out;

  float* wsf = (float*)d_ws;
  char*  wsb = (char*)d_ws;
  float* num  = wsf + NUM_OFF;
  float* xtb  = wsf + XT_OFF;
  float* errb = wsf + ERR_OFF;
  double* sumb = (double*)(wsb + SUM_BYTE);
  int* cntb  = (int*)(wsb + CNT_BYTE);
  int* den   = (int*)(wsb + DEN_BYTE);
  int* order = (int*)(wsb + ORD_BYTE);
  int* flagp = (int*)(wsb + FLAG_BYTE);
  unsigned long long* pm = (unsigned long long*)(wsb + PM_BYTE);

  hipMemsetAsync(wsb + SUM_BYTE, 0, 128, stream);                 // sums/cnts/den
  hipMemsetAsync(wsb + NUM_OFF * 4, 0, BI * DD * DD * 4, stream); // num accumulators
  k_detect<<<1, 256, 0, stream>>>((const unsigned char*)qm, flagp);
  k_pack<<<dim3(NN / 4, BI), 256, 0, stream>>>(qm, km, flagp, pm);
  k_accum_t<<<dim3(RN / 4, BI), 256, 0, stream>>>(kks, pm, wsf, den);
  k_num<<<dim3(4, BI), 256, 0, stream>>>(qk, wsf, num);
  k_xt<<<dim3(NN / 4, BI), 256, 0, stream>>>(qk, num, den, xtb);
  k_err<<<dim3(MM / 64, NN / 64, BI), 256, 0, stream>>>(xtb, kks, pm, errb, sumb, cntb);
  k_rank<<<1, 256, 0, stream>>>(sumb, cntb, num, den, order, out);
  k_quant<<<dim3(NN / 4, KTOP), 256, 0, stream>>>(errb, order, out);
}

// Round 3
// 229.165 us; speedup vs baseline: 2.4570x; 1.1447x over previous
//
#include <hip/hip_runtime.h>
#include <math.h>

// Problem constants (B=1, S=8, N=M=768, D=64, IT=16, RATIO=0.6, THR=0.75, K=8)
#define NN 768
#define MM 768
#define DD 64
#define BI 8            // B*S
#define RN 460          // int(0.6*768) sampled rows/cols
#define KTOP 8
#define MSPLIT 4        // K-splits for the t-GEMM

// Output layout (concatenated flat, return order: ti, tm, topk_err), all f32
static constexpr size_t OFF_TI = 0;                                  // (1,8,768,768)
static constexpr size_t OFF_TM = (size_t)KTOP * NN * MM;             // (1,8,64,64)
static constexpr size_t OFF_TE = OFF_TM + (size_t)KTOP * DD * DD;    // (1,8)

// Workspace layout (float indices, then raw-byte tail)
static constexpr size_t TP_OFF    = 0;                                    // t partials (4,8,460,64)
static constexpr size_t NUM_OFF   = TP_OFF + (size_t)MSPLIT * BI * RN * DD; // num (8,64,64)
static constexpr size_t XT_OFF    = NUM_OFF + (size_t)BI * DD * DD;       // xt (8,768,64)
static constexpr size_t ERR_OFF   = XT_OFF + (size_t)BI * NN * DD;        // err (8,768,768)
static constexpr size_t FLOATS_END = ERR_OFF + (size_t)BI * NN * MM;
static constexpr size_t SUM_BYTE  = FLOATS_END * 4;   // double[8]
static constexpr size_t CNT_BYTE  = SUM_BYTE + 64;    // int[8]
static constexpr size_t DEN_BYTE  = CNT_BYTE + 32;    // int[8]
static constexpr size_t ORD_BYTE  = DEN_BYTE + 32;    // int[8]
static constexpr size_t FLAG_BYTE = ORD_BYTE + 32;    // int[1]
static constexpr size_t PM_BYTE   = SUM_BYTE + 256;   // uint64[8*768*16] packed combined mask

__device__ __forceinline__ int ldm(const void* p, int flag, size_t idx) {
  if (flag) return ((const int*)p)[idx] != 0;
  return ((const unsigned char*)p)[idx] != 0;
}

// Detect mask storage layout: int32 0/1 values have zero bytes at offsets %4 != 0.
__global__ void k_detect(const unsigned char* __restrict__ q, int* __restrict__ flag) {
  __shared__ int found;
  if (threadIdx.x == 0) found = 0;
  __syncthreads();
  int f = 0;
  for (int i = threadIdx.x; i < 4096; i += 256)
    if ((i & 3) && q[i]) f = 1;
  if (f) atomicOr(&found, 1);
  __syncthreads();
  if (threadIdx.x == 0) *flag = found ? 0 : 1;   // 1 => int32 layout
}

// Pack combined mask qm&km into bitmask words: pm[(b*768+i)*16 + w] covers j = w*64..w*64+63.
__global__ __launch_bounds__(256) void k_pack(
    const void* __restrict__ qm, const void* __restrict__ km, const int* __restrict__ flagp,
    unsigned long long* __restrict__ pm) {
  int b = blockIdx.y;
  int i = blockIdx.x * 4 + (threadIdx.x >> 6);
  int lane = threadIdx.x & 63;
  int flag = *flagp;
  size_t row = ((size_t)b * NN + i) * MM;
  size_t prow = ((size_t)b * NN + i) * 16;
#pragma unroll
  for (int w = 0; w < 12; w++) {
    int j = w * 64 + lane;
    int ms = ldm(qm, flag, row + j) & ldm(km, flag, row + j);
    unsigned long long bl = __ballot(ms);
    if (lane == 0) pm[prow + w] = bl;
  }
}

// Kernel A (dense masked GEMM): tpart[s,b,n,e] = sum_{m in split s} mask_bit * y[b,m,e].
// 64n x 64e tile per block, K-split over m (2 chunks of 64 per split). Bit-select as
// sign-extended bitfield -> v_and -> v_add: 3 VALU/MAC, 16 independent accs per thread.
__global__ __launch_bounds__(256) void k_tgemm(
    const float* __restrict__ kks, const unsigned long long* __restrict__ pm,
    float* __restrict__ tpart, int* __restrict__ den) {
  __shared__ float ys[64 * 68];
  int ntile = blockIdx.x;        // 0..7
  int split = blockIdx.y;        // 0..MSPLIT-1
  int b = blockIdx.z;
  int tid = threadIdx.x;
  int e = tid & 63, g = tid >> 6;          // g wave-uniform
  int n0 = ntile * 64 + g * 16;            // this thread's 16 rows
  const float* yb = kks + (size_t)b * MM * DD;
  float acc[16];
#pragma unroll
  for (int i = 0; i < 16; i++) acc[i] = 0.f;
  int cnt = 0;
  for (int c = split * 2; c < split * 2 + 2; c++) {
    int m0 = c * 64;
    __syncthreads();
    for (int q = tid; q < 1024; q += 256) {
      int r = q >> 4, col = (q & 15) * 4;
      *(float4*)&ys[r * 68 + col] = *(const float4*)&yb[(size_t)(m0 + r) * DD + col];
    }
    __syncthreads();
    unsigned wlo[16], whi[16];
#pragma unroll
    for (int i = 0; i < 16; i++) {
      unsigned long long w = pm[((size_t)b * NN + (n0 + i)) * 16 + c];
      if (c == 7) w &= 0xFFFULL;           // m < 460
      wlo[i] = (unsigned)w;
      whi[i] = (unsigned)(w >> 32);
      if (n0 + i < RN) cnt += __builtin_popcountll(w);
    }
#pragma unroll 4
    for (int m = 0; m < 32; m++) {
      float yv = ys[m * 68 + e];
      int yi = __float_as_int(yv);
#pragma unroll
      for (int i = 0; i < 16; i++) {
#if __has_builtin(__builtin_amdgcn_sbfe)
        int sel = __builtin_amdgcn_sbfe((int)wlo[i], (unsigned)m, 1u);
#else
        int sel = ((int)(wlo[i] << (31 - m))) >> 31;
#endif
        acc[i] += __int_as_float(yi & sel);
      }
    }
#pragma unroll 4
    for (int m = 0; m < 32; m++) {
      float yv = ys[(m + 32) * 68 + e];
      int yi = __float_as_int(yv);
#pragma unroll
      for (int i = 0; i < 16; i++) {
#if __has_builtin(__builtin_amdgcn_sbfe)
        int sel = __builtin_amdgcn_sbfe((int)whi[i], (unsigned)m, 1u);
#else
        int sel = ((int)(whi[i] << (31 - m))) >> 31;
#endif
        acc[i] += __int_as_float(yi & sel);
      }
    }
  }
#pragma unroll
  for (int i = 0; i < 16; i++) {
    int n = n0 + i;
    if (n < RN)
      tpart[(((size_t)split * BI + b) * RN + n) * DD + e] = acc[i];
  }
  if (e == 0) atomicAdd(&den[b], cnt);     // one add per wave (cnt only on valid rows)
}

// Kernel B: num[b,d,e] += sum_{n in split} x[n,d]*t[b,n,e]; t = sum of 4 partials.
__global__ __launch_bounds__(256) void k_num(
    const float* __restrict__ qk, const float* __restrict__ tpart, float* __restrict__ num) {
  __shared__ float xs[16 * 64];
  __shared__ float ts[16 * 64];
  int b = blockIdx.y;
  int n_beg = blockIdx.x * 115, n_end = n_beg + 115;   // 4*115 = 460
  int tid = threadIdx.x;
  int e = tid & 63, dg = tid >> 6;
  float acc[16];
#pragma unroll
  for (int i = 0; i < 16; i++) acc[i] = 0.f;
  for (int c0 = n_beg; c0 < n_end; c0 += 16) {
    for (int l = tid; l < 1024; l += 256) {
      int r = l >> 6, col = l & 63;
      int n = c0 + r;
      float tv = 0.f, xv = 0.f;
      if (n < n_end) {
        xv = qk[(size_t)n * DD + col];
#pragma unroll
        for (int s = 0; s < MSPLIT; s++)
          tv += tpart[(((size_t)s * BI + b) * RN + n) * DD + col];
      }
      xs[l] = xv;
      ts[l] = tv;
    }
    __syncthreads();
#pragma unroll 4
    for (int r = 0; r < 16; r++) {
      float tv = ts[r * 64 + e];
#pragma unroll
      for (int i = 0; i < 16; i++) acc[i] += xs[r * 64 + dg + i * 4] * tv;
    }
    __syncthreads();
  }
#pragma unroll
  for (int i = 0; i < 16; i++) {
    int d = dg + i * 4;
    atomicAdd(&num[(size_t)b * (DD * DD) + (size_t)d * DD + e], acc[i]);
  }
}

// Kernel C: xt[b,n,e] = sum_d x[n,d]*num[b,d,e]/den[b]
__global__ __launch_bounds__(256) void k_xt(
    const float* __restrict__ qk, const float* __restrict__ num, const int* __restrict__ den,
    float* __restrict__ xt) {
  __shared__ float ml[DD * DD];
  int b = blockIdx.y;
  int tid = threadIdx.x;
  float inv = 1.f / ((float)den[b] + 1e-6f);
  for (int l = tid; l < DD * DD; l += 256) ml[l] = num[(size_t)b * DD * DD + l] * inv;
  __syncthreads();
  int n = blockIdx.x * 4 + (tid >> 6);
  int lane = tid & 63;
  float acc = 0.f;
#pragma unroll 8
  for (int d = 0; d < DD; d++) acc += qk[(size_t)n * DD + d] * ml[d * DD + lane];
  xt[((size_t)b * NN + n) * DD + lane] = acc;
}

// Kernel D: err[b,i,j] = mask ? ||xt_i||^2 + ||y_j||^2 - 2*xt_i.y_j : +INF
__global__ __launch_bounds__(256) void k_err(
    const float* __restrict__ xt, const float* __restrict__ kks,
    const unsigned long long* __restrict__ pm,
    float* __restrict__ err, double* __restrict__ sumb, int* __restrict__ cntb) {
  __shared__ float As[64 * 68];
  __shared__ float Bs[64 * 68];
  __shared__ float xx_s[64], yy_s[64];
  __shared__ float rsum[256];
  __shared__ int rcnt[256];
  int b = blockIdx.z;
  int wj = blockIdx.x;
  int i0 = blockIdx.y * 64, j0 = wj * 64;
  int tid = threadIdx.x;
  int tx = tid & 15, ty = tid >> 4;
  const float* xb = xt + ((size_t)b * NN + i0) * DD;
  const float* yb = kks + ((size_t)b * MM + j0) * DD;
  for (int q = tid; q < 1024; q += 256) {
    int r = q >> 4, c = q & 15;
    float4 va = ((const float4*)(xb + (size_t)r * DD))[c];
    float4 vb = ((const float4*)(yb + (size_t)r * DD))[c];
    *(float4*)&As[r * 68 + c * 4] = va;
    *(float4*)&Bs[r * 68 + c * 4] = vb;
  }
  __syncthreads();
  if (tid < 64) {
    float s = 0.f;
#pragma unroll 8
    for (int k2 = 0; k2 < 64; k2++) { float v = As[tid * 68 + k2]; s += v * v; }
    xx_s[tid] = s;
  } else if (tid < 128) {
    int r = tid - 64;
    float s = 0.f;
#pragma unroll 8
    for (int k2 = 0; k2 < 64; k2++) { float v = Bs[r * 68 + k2]; s += v * v; }
    yy_s[r] = s;
  }
  __syncthreads();
  float acc[4][4];
#pragma unroll
  for (int ii = 0; ii < 4; ii++)
#pragma unroll
    for (int jj = 0; jj < 4; jj++) acc[ii][jj] = 0.f;
  for (int k2 = 0; k2 < 64; k2 += 4) {
    float4 av[4], bv[4];
#pragma unroll
    for (int ii = 0; ii < 4; ii++) av[ii] = *(const float4*)&As[(ty + 16 * ii) * 68 + k2];
#pragma unroll
    for (int jj = 0; jj < 4; jj++) bv[jj] = *(const float4*)&Bs[(tx + 16 * jj) * 68 + k2];
#pragma unroll
    for (int ii = 0; ii < 4; ii++)
#pragma unroll
      for (int jj = 0; jj < 4; jj++)
        acc[ii][jj] += av[ii].x * bv[jj].x + av[ii].y * bv[jj].y +
                       av[ii].z * bv[jj].z + av[ii].w * bv[jj].w;
  }
  const float INF = __builtin_inff();
  float psum = 0.f;
  int pcnt = 0;
#pragma unroll
  for (int ii = 0; ii < 4; ii++) {
    int i = i0 + ty + 16 * ii;
    unsigned long long word = pm[((size_t)b * NN + i) * 16 + wj];
#pragma unroll
    for (int jj = 0; jj < 4; jj++) {
      int j = j0 + tx + 16 * jj;
      size_t idx = ((size_t)b * NN + i) * MM + j;
      int ms = (int)((word >> (tx + 16 * jj)) & 1ULL);
      float v = xx_s[ty + 16 * ii] + yy_s[tx + 16 * jj] - 2.f * acc[ii][jj];
      if (ms) { err[idx] = v; psum += v; pcnt++; }
      else    { err[idx] = INF; }
    }
  }
  rsum[tid] = psum;
  rcnt[tid] = pcnt;
  __syncthreads();
  for (int s = 128; s > 0; s >>= 1) {
    if (tid < s) { rsum[tid] += rsum[tid + s]; rcnt[tid] += rcnt[tid + s]; }
    __syncthreads();
  }
  if (tid == 0) {
    atomicAdd(&sumb[b], (double)rsum[0]);
    atomicAdd(&cntb[b], rcnt[0]);
  }
}

// Kernel E: rank batches by avg err descending (== top_k with K=S); write topk_err + models.
__global__ __launch_bounds__(256) void k_rank(
    const double* __restrict__ sumb, const int* __restrict__ cntb,
    const float* __restrict__ num, const int* __restrict__ den,
    int* __restrict__ order, float* __restrict__ out) {
  __shared__ int ord_s[BI];
  __shared__ float invd_s[BI];
  if (threadIdx.x == 0) {
    float avg[BI];
    bool used[BI];
    for (int b = 0; b < BI; b++) { avg[b] = (float)(sumb[b] / (double)cntb[b]); used[b] = false; }
    for (int k = 0; k < KTOP; k++) {
      int best = -1;
      float bv = -__builtin_inff();
      for (int b = 0; b < BI; b++)
        if (!used[b] && avg[b] > bv) { bv = avg[b]; best = b; }
      used[best] = true;
      ord_s[k] = best;
      order[k] = best;
      invd_s[k] = 1.f / ((float)den[best] + 1e-6f);
      out[OFF_TE + k] = avg[best];
    }
  }
  __syncthreads();
  for (int l = threadIdx.x; l < KTOP * DD * DD; l += 256) {
    int k = l >> 12;
    out[OFF_TM + l] = num[(size_t)ord_s[k] * DD * DD + (l & (DD * DD - 1))] * invd_s[k];
  }
}

__device__ __forceinline__ unsigned f2key(float f) {
  unsigned u = __float_as_uint(f);
  return (u & 0x80000000u) ? ~u : (u | 0x80000000u);
}
__device__ __forceinline__ float key2f(unsigned k) {
  unsigned u = (k & 0x80000000u) ? (k ^ 0x80000000u) : ~k;
  return __uint_as_float(u);
}

// Kernel F: one WAVE per (k,n) row; exact quantile via ballot binary search, no LDS/barriers.
__global__ __launch_bounds__(256) void k_quant(
    const float* __restrict__ err, const int* __restrict__ order, float* __restrict__ out) {
  int kk = blockIdx.y;
  int n = blockIdx.x * 4 + (threadIdx.x >> 6);
  int lane = threadIdx.x & 63;
  int b = order[kk];
  const float* row = err + ((size_t)b * NN + n) * MM;
  const float INF = __builtin_inff();
  float v[12];
  unsigned key[12];
#pragma unroll
  for (int w = 0; w < 3; w++) {
    float4 f4 = ((const float4*)row)[w * 64 + lane];
    v[w * 4 + 0] = f4.x; v[w * 4 + 1] = f4.y; v[w * 4 + 2] = f4.z; v[w * 4 + 3] = f4.w;
  }
  int cnt = 0;
#pragma unroll
  for (int r = 0; r < 12; r++) {
    key[r] = f2key(v[r]);
    cnt += __builtin_popcountll(__ballot(v[r] < INF));
  }
  float thr;
  if (cnt == 0) {
    thr = -INF;
  } else {
    float pos = 0.75f * (float)(cnt - 1);
    int k0 = (int)pos;
    float f = pos - (float)k0;
    unsigned lo = 0u, hi = 0xFFFFFFFFu;
    int target = k0 + 1;
    while (lo < hi) {
      unsigned mid = lo + ((hi - lo) >> 1);
      int c = 0;
#pragma unroll
      for (int r = 0; r < 12; r++) c += __builtin_popcountll(__ballot(key[r] <= mid));
      if (c >= target) hi = mid; else lo = mid + 1;
    }
    unsigned ka = lo;
    float a = key2f(ka);
    float b2;
    if (k0 + 1 >= cnt) {
      b2 = a;
    } else {
      int c1 = 0;
#pragma unroll
      for (int r = 0; r < 12; r++) c1 += __builtin_popcountll(__ballot(key[r] <= ka));
      if (c1 >= k0 + 2) {
        b2 = a;
      } else {
        unsigned mn = 0xFFFFFFFFu;
#pragma unroll
        for (int r = 0; r < 12; r++) mn = min(mn, (key[r] > ka) ? key[r] : 0xFFFFFFFFu);
#pragma unroll
        for (int off = 32; off > 0; off >>= 1) {
          unsigned o = (unsigned)__shfl_xor((int)mn, off);
          mn = min(mn, o);
        }
        b2 = key2f(mn);
      }
    }
    thr = a + f * (b2 - a);
  }
  float* orow = out + OFF_TI + ((size_t)kk * NN + n) * MM;
#pragma unroll
  for (int w = 0; w < 3; w++) {
    float4 o;
    o.x = (v[w * 4 + 0] < thr) ? 1.f : 0.f;
    o.y = (v[w * 4 + 1] < thr) ? 1.f : 0.f;
    o.z = (v[w * 4 + 2] < thr) ? 1.f : 0.f;
    o.w = (v[w * 4 + 3] < thr) ? 1.f : 0.f;
    ((float4*)orow)[w * 64 + lane] = o;
  }
}

extern "C" void kernel_launch(void* const* d_in, const int* in_sizes, int n_in,
                              void* d_out, int out_size, void* d_ws, size_t ws_size,
                              hipStream_t stream) {
  (void)in_sizes; (void)n_in; (void)out_size; (void)ws_size;
  const float* qk  = (const float*)d_in[0];   // (1,768,64)
  const float* kks = (const float*)d_in[1];   // (1,8,768,64)
  const void*  qm  = d_in[2];                 // (8,768,768) bool/int
  const void*  km  = d_in[3];                 // (8,768,768) bool/int
  // perm1/perm2 unused: permutations make the solver sums iteration-invariant.
  float* out = (float*)d_out;

  float* wsf = (float*)d_ws;
  char*  wsb = (char*)d_ws;
  float* tpart = wsf + TP_OFF;
  float* num  = wsf + NUM_OFF;
  float* xtb  = wsf + XT_OFF;
  float* errb = wsf + ERR_OFF;
  double* sumb = (double*)(wsb + SUM_BYTE);
  int* cntb  = (int*)(wsb + CNT_BYTE);
  int* den   = (int*)(wsb + DEN_BYTE);
  int* order = (int*)(wsb + ORD_BYTE);
  int* flagp = (int*)(wsb + FLAG_BYTE);
  unsigned long long* pm = (unsigned long long*)(wsb + PM_BYTE);

  hipMemsetAsync(wsb + SUM_BYTE, 0, 128, stream);                    // sums/cnts/den
  hipMemsetAsync(wsb + NUM_OFF * 4, 0, BI * DD * DD * 4, stream);    // num accumulators
  k_detect<<<1, 256, 0, stream>>>((const unsigned char*)qm, flagp);
  k_pack<<<dim3(NN / 4, BI), 256, 0, stream>>>(qm, km, flagp, pm);
  k_tgemm<<<dim3(8, MSPLIT, BI), 256, 0, stream>>>(kks, pm, tpart, den);
  k_num<<<dim3(4, BI), 256, 0, stream>>>(qk, tpart, num);
  k_xt<<<dim3(NN / 4, BI), 256, 0, stream>>>(qk, num, den, xtb);
  k_err<<<dim3(MM / 64, NN / 64, BI), 256, 0, stream>>>(xtb, kks, pm, errb, sumb, cntb);
  k_rank<<<1, 256, 0, stream>>>(sumb, cntb, num, den, order, out);
  k_quant<<<dim3(NN / 4, KTOP), 256, 0, stream>>>(errb, order, out);
}

// Round 4
// 215.870 us; speedup vs baseline: 2.6083x; 1.0616x over previous
//
#include <hip/hip_runtime.h>
#include <math.h>

// Problem constants (B=1, S=8, N=M=768, D=64, IT=16, RATIO=0.6, THR=0.75, K=8)
#define NN 768
#define MM 768
#define DD 64
#define BI 8            // B*S
#define RN 460          // int(0.6*768) sampled rows/cols
#define KTOP 8
#define MSPLIT 4        // K-splits for the t-GEMM

// Output layout (concatenated flat, return order: ti, tm, topk_err), all f32
static constexpr size_t OFF_TI = 0;                                  // (1,8,768,768)
static constexpr size_t OFF_TM = (size_t)KTOP * NN * MM;             // (1,8,64,64)
static constexpr size_t OFF_TE = OFF_TM + (size_t)KTOP * DD * DD;    // (1,8)

// Workspace layout (float indices, then raw-byte tail). No memsets needed:
// every location is written before it is read (partials, not atomics).
static constexpr size_t TP_OFF    = 0;                                      // tpart (4,8,460,64)
static constexpr size_t NUMP_OFF  = TP_OFF + (size_t)MSPLIT * BI * RN * DD; // numpart (8,8,64,64)
static constexpr size_t MODEL_OFF = NUMP_OFF + (size_t)8 * BI * DD * DD;    // model (8,64,64) final
static constexpr size_t XT_OFF    = MODEL_OFF + (size_t)BI * DD * DD;       // xt (8,768,64)
static constexpr size_t ERR_OFF   = XT_OFF + (size_t)BI * NN * DD;          // err (8,768,768)
static constexpr size_t FLOATS_END = ERR_OFF + (size_t)BI * NN * MM;
static constexpr size_t ERRP_SUM_BYTE = FLOATS_END * 4;                 // float[1152]
static constexpr size_t ERRP_CNT_BYTE = ERRP_SUM_BYTE + 1152 * 4;       // int[1152]
static constexpr size_t DENP_BYTE     = ERRP_CNT_BYTE + 1152 * 4;       // int[256]
static constexpr size_t ORD_BYTE      = DENP_BYTE + 256 * 4;            // int[8]
static constexpr size_t PM_BYTE       = ORD_BYTE + 32;                  // uint64[8*768*16]

__device__ __forceinline__ int ldm(const void* p, int flag, size_t idx) {
  if (flag) return ((const int*)p)[idx] != 0;
  return ((const unsigned char*)p)[idx] != 0;
}

// Pack combined mask qm&km into bitmask words: pm[(b*768+i)*16 + w] covers j = w*64..63.
// Mask storage layout (bool-byte vs int32) detected inline per block from the first 4 KB
// of qm (L2-hot): int32 0/1 data has zero bytes at offsets %4 != 0.
__global__ __launch_bounds__(256) void k_pack(
    const void* __restrict__ qm, const void* __restrict__ km,
    unsigned long long* __restrict__ pm) {
  __shared__ int flag_sh;
  int tid = threadIdx.x;
  if (tid == 0) flag_sh = 0;
  __syncthreads();
  const unsigned* qw = (const unsigned*)qm;
  int f = 0;
  for (int i = tid; i < 1024; i += 256)
    if (qw[i] & 0xFFFFFF00u) f = 1;          // nonzero high byte => byte layout
  if (__ballot(f) && (tid & 63) == 0) atomicOr(&flag_sh, 1);
  __syncthreads();
  int flag = flag_sh ? 0 : 1;                 // 1 => int32 layout
  int b = blockIdx.y;
  int i = blockIdx.x * 4 + (tid >> 6);
  int lane = tid & 63;
  size_t row = ((size_t)b * NN + i) * MM;
  size_t prow = ((size_t)b * NN + i) * 16;
#pragma unroll
  for (int w = 0; w < 12; w++) {
    int j = w * 64 + lane;
    int ms = ldm(qm, flag, row + j) & ldm(km, flag, row + j);
    unsigned long long bl = __ballot(ms);
    if (lane == 0) pm[prow + w] = bl;
  }
}

// Kernel A (dense masked GEMM): tpart[s,b,n,e] = sum_{m in split s} mask_bit * y[b,m,e].
// 64n x 64e tile per block; per-block mask popcount -> denp[b*32 + split*8 + ntile].
__global__ __launch_bounds__(256) void k_tgemm(
    const float* __restrict__ kks, const unsigned long long* __restrict__ pm,
    float* __restrict__ tpart, int* __restrict__ denp) {
  __shared__ float ys[64 * 68];
  __shared__ int cnt_sh[4];
  int ntile = blockIdx.x;        // 0..7
  int split = blockIdx.y;        // 0..MSPLIT-1
  int b = blockIdx.z;
  int tid = threadIdx.x;
  int e = tid & 63, g = tid >> 6;          // g wave-uniform
  int n0 = ntile * 64 + g * 16;            // this thread's 16 rows
  const float* yb = kks + (size_t)b * MM * DD;
  float acc[16];
#pragma unroll
  for (int i = 0; i < 16; i++) acc[i] = 0.f;
  int cnt = 0;
  for (int c = split * 2; c < split * 2 + 2; c++) {
    int m0 = c * 64;
    __syncthreads();
    for (int q = tid; q < 1024; q += 256) {
      int r = q >> 4, col = (q & 15) * 4;
      *(float4*)&ys[r * 68 + col] = *(const float4*)&yb[(size_t)(m0 + r) * DD + col];
    }
    __syncthreads();
    unsigned wlo[16], whi[16];
#pragma unroll
    for (int i = 0; i < 16; i++) {
      unsigned long long w = pm[((size_t)b * NN + (n0 + i)) * 16 + c];
      if (c == 7) w &= 0xFFFULL;           // m < 460
      wlo[i] = (unsigned)w;
      whi[i] = (unsigned)(w >> 32);
      if (n0 + i < RN) cnt += __builtin_popcountll(w);
    }
#pragma unroll 4
    for (int m = 0; m < 32; m++) {
      float yv = ys[m * 68 + e];
      int yi = __float_as_int(yv);
#pragma unroll
      for (int i = 0; i < 16; i++) {
        int sel = ((int)(wlo[i] << (31 - m))) >> 31;
        acc[i] += __int_as_float(yi & sel);
      }
    }
#pragma unroll 4
    for (int m = 0; m < 32; m++) {
      float yv = ys[(m + 32) * 68 + e];
      int yi = __float_as_int(yv);
#pragma unroll
      for (int i = 0; i < 16; i++) {
        int sel = ((int)(whi[i] << (31 - m))) >> 31;
        acc[i] += __int_as_float(yi & sel);
      }
    }
  }
#pragma unroll
  for (int i = 0; i < 16; i++) {
    int n = n0 + i;
    if (n < RN)
      tpart[(((size_t)split * BI + b) * RN + n) * DD + e] = acc[i];
  }
  if (e == 0) cnt_sh[g] = cnt;             // all lanes of a wave hold identical cnt
  __syncthreads();
  if (tid == 0)
    denp[b * 32 + split * 8 + ntile] = cnt_sh[0] + cnt_sh[1] + cnt_sh[2] + cnt_sh[3];
}

// Kernel B: numpart[c,b,d,e] = sum_{n in chunk c} x[n,d]*t[b,n,e]; t = sum of 4 tpart splits.
__global__ __launch_bounds__(256) void k_num(
    const float* __restrict__ qk, const float* __restrict__ tpart, float* __restrict__ numpart) {
  __shared__ float xs[16 * 64];
  __shared__ float ts[16 * 64];
  int b = blockIdx.y;
  int c0 = blockIdx.x * 64;                // 8 chunks of 64 cover 512 >= 460 (guarded)
  int tid = threadIdx.x;
  int e = tid & 63, dg = tid >> 6;
  float acc[16];
#pragma unroll
  for (int i = 0; i < 16; i++) acc[i] = 0.f;
  for (int it = 0; it < 4; it++) {
    int base = c0 + it * 16;
    for (int l = tid; l < 1024; l += 256) {
      int r = l >> 6, col = l & 63;
      int n = base + r;
      float tv = 0.f, xv = 0.f;
      if (n < RN) {
        xv = qk[(size_t)n * DD + col];
#pragma unroll
        for (int s = 0; s < MSPLIT; s++)
          tv += tpart[(((size_t)s * BI + b) * RN + n) * DD + col];
      }
      xs[l] = xv;
      ts[l] = tv;
    }
    __syncthreads();
#pragma unroll 4
    for (int r = 0; r < 16; r++) {
      float tv = ts[r * 64 + e];
#pragma unroll
      for (int i = 0; i < 16; i++) acc[i] += xs[r * 64 + dg + i * 4] * tv;
    }
    __syncthreads();
  }
#pragma unroll
  for (int i = 0; i < 16; i++) {
    int d = dg + i * 4;
    numpart[((size_t)blockIdx.x * BI + b) * (DD * DD) + (size_t)d * DD + e] = acc[i];
  }
}

// Kernel B2: model[b] = (sum_c numpart[c,b]) / (den[b]+1e-6); den[b] = sum of 32 denp entries.
__global__ __launch_bounds__(256) void k_model(
    const float* __restrict__ numpart, const int* __restrict__ denp, float* __restrict__ model) {
  __shared__ float inv_sh;
  int b = blockIdx.x;
  int tid = threadIdx.x;
  if (tid < 64) {
    int v = (tid < 32) ? denp[b * 32 + tid] : 0;
#pragma unroll
    for (int o = 32; o > 0; o >>= 1) v += __shfl_xor(v, o);
    if (tid == 0) inv_sh = 1.f / ((float)v + 1e-6f);
  }
  __syncthreads();
  float inv = inv_sh;
  for (int l = tid; l < DD * DD; l += 256) {
    float s = 0.f;
#pragma unroll
    for (int c = 0; c < 8; c++) s += numpart[((size_t)c * BI + b) * (DD * DD) + l];
    model[(size_t)b * DD * DD + l] = s * inv;
  }
}

// Kernel C: xt[b,n,e] = sum_d x[n,d]*model[b,d,e]
__global__ __launch_bounds__(256) void k_xt(
    const float* __restrict__ qk, const float* __restrict__ model, float* __restrict__ xt) {
  __shared__ float ml[DD * DD];
  int b = blockIdx.y;
  int tid = threadIdx.x;
  for (int l = tid; l < DD * DD; l += 256) ml[l] = model[(size_t)b * DD * DD + l];
  __syncthreads();
  int n = blockIdx.x * 4 + (tid >> 6);
  int lane = tid & 63;
  float acc = 0.f;
#pragma unroll 8
  for (int d = 0; d < DD; d++) acc += qk[(size_t)n * DD + d] * ml[d * DD + lane];
  xt[((size_t)b * NN + n) * DD + lane] = acc;
}

// Kernel D: err[b,i,j] = mask ? ||xt_i||^2 + ||y_j||^2 - 2*xt_i.y_j : +INF
// Per-block masked sum/count -> errp partials (no atomics, deterministic).
__global__ __launch_bounds__(256) void k_err(
    const float* __restrict__ xt, const float* __restrict__ kks,
    const unsigned long long* __restrict__ pm,
    float* __restrict__ err, float* __restrict__ errp_sum, int* __restrict__ errp_cnt) {
  __shared__ float As[64 * 68];
  __shared__ float Bs[64 * 68];
  __shared__ float xx_s[64], yy_s[64];
  __shared__ float rsum[256];
  __shared__ int rcnt[256];
  int b = blockIdx.z;
  int wj = blockIdx.x;
  int i0 = blockIdx.y * 64, j0 = wj * 64;
  int tid = threadIdx.x;
  int tx = tid & 15, ty = tid >> 4;
  const float* xb = xt + ((size_t)b * NN + i0) * DD;
  const float* yb = kks + ((size_t)b * MM + j0) * DD;
  for (int q = tid; q < 1024; q += 256) {
    int r = q >> 4, c = q & 15;
    float4 va = ((const float4*)(xb + (size_t)r * DD))[c];
    float4 vb = ((const float4*)(yb + (size_t)r * DD))[c];
    *(float4*)&As[r * 68 + c * 4] = va;
    *(float4*)&Bs[r * 68 + c * 4] = vb;
  }
  __syncthreads();
  if (tid < 64) {
    float s = 0.f;
#pragma unroll 8
    for (int k2 = 0; k2 < 64; k2++) { float v = As[tid * 68 + k2]; s += v * v; }
    xx_s[tid] = s;
  } else if (tid < 128) {
    int r = tid - 64;
    float s = 0.f;
#pragma unroll 8
    for (int k2 = 0; k2 < 64; k2++) { float v = Bs[r * 68 + k2]; s += v * v; }
    yy_s[r] = s;
  }
  __syncthreads();
  float acc[4][4];
#pragma unroll
  for (int ii = 0; ii < 4; ii++)
#pragma unroll
    for (int jj = 0; jj < 4; jj++) acc[ii][jj] = 0.f;
  for (int k2 = 0; k2 < 64; k2 += 4) {
    float4 av[4], bv[4];
#pragma unroll
    for (int ii = 0; ii < 4; ii++) av[ii] = *(const float4*)&As[(ty + 16 * ii) * 68 + k2];
#pragma unroll
    for (int jj = 0; jj < 4; jj++) bv[jj] = *(const float4*)&Bs[(tx + 16 * jj) * 68 + k2];
#pragma unroll
    for (int ii = 0; ii < 4; ii++)
#pragma unroll
      for (int jj = 0; jj < 4; jj++)
        acc[ii][jj] += av[ii].x * bv[jj].x + av[ii].y * bv[jj].y +
                       av[ii].z * bv[jj].z + av[ii].w * bv[jj].w;
  }
  const float INF = __builtin_inff();
  float psum = 0.f;
  int pcnt = 0;
#pragma unroll
  for (int ii = 0; ii < 4; ii++) {
    int i = i0 + ty + 16 * ii;
    unsigned long long word = pm[((size_t)b * NN + i) * 16 + wj];
#pragma unroll
    for (int jj = 0; jj < 4; jj++) {
      int j = j0 + tx + 16 * jj;
      size_t idx = ((size_t)b * NN + i) * MM + j;
      int ms = (int)((word >> (tx + 16 * jj)) & 1ULL);
      float v = xx_s[ty + 16 * ii] + yy_s[tx + 16 * jj] - 2.f * acc[ii][jj];
      if (ms) { err[idx] = v; psum += v; pcnt++; }
      else    { err[idx] = INF; }
    }
  }
  rsum[tid] = psum;
  rcnt[tid] = pcnt;
  __syncthreads();
  for (int s = 128; s > 0; s >>= 1) {
    if (tid < s) { rsum[tid] += rsum[tid + s]; rcnt[tid] += rcnt[tid + s]; }
    __syncthreads();
  }
  if (tid == 0) {
    int blk = b * 144 + blockIdx.y * 12 + wj;
    errp_sum[blk] = rsum[0];
    errp_cnt[blk] = rcnt[0];
  }
}

// Kernel E: sum errp partials -> avg[b]; rank descending (== lax.top_k, K=S);
// write topk_err + gathered models; store order for kernel F.
__global__ __launch_bounds__(256) void k_rank(
    const float* __restrict__ errp_sum, const int* __restrict__ errp_cnt,
    const float* __restrict__ model, int* __restrict__ order, float* __restrict__ out) {
  __shared__ float red[256];
  __shared__ int redi[256];
  __shared__ float avg_sh[BI];
  __shared__ int ord_s[BI];
  int tid = threadIdx.x;
  for (int b = 0; b < BI; b++) {
    red[tid] = (tid < 144) ? errp_sum[b * 144 + tid] : 0.f;
    redi[tid] = (tid < 144) ? errp_cnt[b * 144 + tid] : 0;
    __syncthreads();
    for (int s = 128; s > 0; s >>= 1) {
      if (tid < s) { red[tid] += red[tid + s]; redi[tid] += redi[tid + s]; }
      __syncthreads();
    }
    if (tid == 0) avg_sh[b] = red[0] / (float)redi[0];
    __syncthreads();
  }
  if (tid == 0) {
    bool used[BI];
    for (int b = 0; b < BI; b++) used[b] = false;
    for (int k = 0; k < KTOP; k++) {
      int best = -1;
      float bv = -__builtin_inff();
      for (int b = 0; b < BI; b++)
        if (!used[b] && avg_sh[b] > bv) { bv = avg_sh[b]; best = b; }
      used[best] = true;
      ord_s[k] = best;
      order[k] = best;
      out[OFF_TE + k] = avg_sh[best];
    }
  }
  __syncthreads();
  for (int l = tid; l < KTOP * DD * DD; l += 256) {
    int k = l >> 12;
    out[OFF_TM + l] = model[(size_t)ord_s[k] * DD * DD + (l & (DD * DD - 1))];
  }
}

__device__ __forceinline__ unsigned f2key(float f) {
  unsigned u = __float_as_uint(f);
  return (u & 0x80000000u) ? ~u : (u | 0x80000000u);
}
__device__ __forceinline__ float key2f(unsigned k) {
  unsigned u = (k & 0x80000000u) ? (k ^ 0x80000000u) : ~k;
  return __uint_as_float(u);
}

// Kernel F: one WAVE per (k,n) row; exact quantile via ballot binary search, no LDS/barriers.
__global__ __launch_bounds__(256) void k_quant(
    const float* __restrict__ err, const int* __restrict__ order, float* __restrict__ out) {
  int kk = blockIdx.y;
  int n = blockIdx.x * 4 + (threadIdx.x >> 6);
  int lane = threadIdx.x & 63;
  int b = order[kk];
  const float* row = err + ((size_t)b * NN + n) * MM;
  const float INF = __builtin_inff();
  float v[12];
  unsigned key[12];
#pragma unroll
  for (int w = 0; w < 3; w++) {
    float4 f4 = ((const float4*)row)[w * 64 + lane];
    v[w * 4 + 0] = f4.x; v[w * 4 + 1] = f4.y; v[w * 4 + 2] = f4.z; v[w * 4 + 3] = f4.w;
  }
  int cnt = 0;
#pragma unroll
  for (int r = 0; r < 12; r++) {
    key[r] = f2key(v[r]);
    cnt += __builtin_popcountll(__ballot(v[r] < INF));
  }
  float thr;
  if (cnt == 0) {
    thr = -INF;
  } else {
    float pos = 0.75f * (float)(cnt - 1);
    int k0 = (int)pos;
    float f = pos - (float)k0;
    unsigned lo = 0u, hi = 0xFFFFFFFFu;
    int target = k0 + 1;
    while (lo < hi) {
      unsigned mid = lo + ((hi - lo) >> 1);
      int c = 0;
#pragma unroll
      for (int r = 0; r < 12; r++) c += __builtin_popcountll(__ballot(key[r] <= mid));
      if (c >= target) hi = mid; else lo = mid + 1;
    }
    unsigned ka = lo;
    float a = key2f(ka);
    float b2;
    if (k0 + 1 >= cnt) {
      b2 = a;
    } else {
      int c1 = 0;
#pragma unroll
      for (int r = 0; r < 12; r++) c1 += __builtin_popcountll(__ballot(key[r] <= ka));
      if (c1 >= k0 + 2) {
        b2 = a;
      } else {
        unsigned mn = 0xFFFFFFFFu;
#pragma unroll
        for (int r = 0; r < 12; r++) mn = min(mn, (key[r] > ka) ? key[r] : 0xFFFFFFFFu);
#pragma unroll
        for (int off = 32; off > 0; off >>= 1) {
          unsigned o = (unsigned)__shfl_xor((int)mn, off);
          mn = min(mn, o);
        }
        b2 = key2f(mn);
      }
    }
    thr = a + f * (b2 - a);
  }
  float* orow = out + OFF_TI + ((size_t)kk * NN + n) * MM;
#pragma unroll
  for (int w = 0; w < 3; w++) {
    float4 o;
    o.x = (v[w * 4 + 0] < thr) ? 1.f : 0.f;
    o.y = (v[w * 4 + 1] < thr) ? 1.f : 0.f;
    o.z = (v[w * 4 + 2] < thr) ? 1.f : 0.f;
    o.w = (v[w * 4 + 3] < thr) ? 1.f : 0.f;
    ((float4*)orow)[w * 64 + lane] = o;
  }
}

extern "C" void kernel_launch(void* const* d_in, const int* in_sizes, int n_in,
                              void* d_out, int out_size, void* d_ws, size_t ws_size,
                              hipStream_t stream) {
  (void)in_sizes; (void)n_in; (void)out_size; (void)ws_size;
  const float* qk  = (const float*)d_in[0];   // (1,768,64)
  const float* kks = (const float*)d_in[1];   // (1,8,768,64)
  const void*  qm  = d_in[2];                 // (8,768,768) bool/int
  const void*  km  = d_in[3];                 // (8,768,768) bool/int
  // perm1/perm2 unused: permutations make the solver sums iteration-invariant.
  float* out = (float*)d_out;

  float* wsf = (float*)d_ws;
  char*  wsb = (char*)d_ws;
  float* tpart   = wsf + TP_OFF;
  float* numpart = wsf + NUMP_OFF;
  float* model   = wsf + MODEL_OFF;
  float* xtb     = wsf + XT_OFF;
  float* errb    = wsf + ERR_OFF;
  float* errp_sum = (float*)(wsb + ERRP_SUM_BYTE);
  int* errp_cnt = (int*)(wsb + ERRP_CNT_BYTE);
  int* denp  = (int*)(wsb + DENP_BYTE);
  int* order = (int*)(wsb + ORD_BYTE);
  unsigned long long* pm = (unsigned long long*)(wsb + PM_BYTE);

  k_pack<<<dim3(NN / 4, BI), 256, 0, stream>>>(qm, km, pm);
  k_tgemm<<<dim3(8, MSPLIT, BI), 256, 0, stream>>>(kks, pm, tpart, denp);
  k_num<<<dim3(8, BI), 256, 0, stream>>>(qk, tpart, numpart);
  k_model<<<BI, 256, 0, stream>>>(numpart, denp, model);
  k_xt<<<dim3(NN / 4, BI), 256, 0, stream>>>(qk, model, xtb);
  k_err<<<dim3(MM / 64, NN / 64, BI), 256, 0, stream>>>(xtb, kks, pm, errb, errp_sum, errp_cnt);
  k_rank<<<1, 256, 0, stream>>>(errp_sum, errp_cnt, model, order, out);
  k_quant<<<dim3(NN / 4, KTOP), 256, 0, stream>>>(errb, order, out);
}